// Round 4
// baseline (474.292 us; speedup 1.0000x reference)
//
#include <hip/hip_runtime.h>
#include <stdint.h>

#define S_DIM 4096
#define K_TOP 64
#define THREADS 256
#define EPT 16           // elements per thread = 4096/256
#define CAND_CAP 256

typedef float f4v __attribute__((ext_vector_type(4)));
typedef int   i4v __attribute__((ext_vector_type(4)));

// Pre-fill ones into the scatter-target strip only: cols [0,64) of every row.
// B*S rows * 64 ints = 4 MiB. Must complete before any scatter (same stream
// => serialized). One int4 (16 B) per thread.
__global__ __launch_bounds__(256) void prefill_edge_kernel(i4v* __restrict__ out, int nrows) {
    int L = blockIdx.x * blockDim.x + threadIdx.x;   // 0 .. nrows*16-1
    if (L >= nrows * 16) return;
    int row = L >> 4;          // global row (b*S + s)
    int q   = L & 15;          // which int4 within the first 64 ints
    i4v ones = {1, 1, 1, 1};
    __builtin_nontemporal_store(ones, out + (size_t)row * (S_DIM / 4) + q);
}

__device__ __forceinline__ unsigned long long shfl_xor_u64(unsigned long long v, int m) {
    uint32_t lo = (uint32_t)v, hi = (uint32_t)(v >> 32);
    lo = __shfl_xor(lo, m, 64);
    hi = __shfl_xor(hi, m, 64);
    return ((unsigned long long)hi << 32) | lo;
}

__global__ __launch_bounds__(256) void topk_scatter_kernel(const float* __restrict__ scores,
                                                           int* __restrict__ out) {
    const int row  = blockIdx.x;          // b*S + s
    const int b    = row >> 12;           // row / 4096
    const int t    = threadIdx.x;
    const int lane = t & 63;
    const int wid  = t >> 6;

    __shared__ uint32_t sh_w16[4];
    __shared__ __align__(16) unsigned long long cand[CAND_CAP];
    __shared__ uint32_t sh_count;
    __shared__ unsigned long long sh_wbest[4];
    __shared__ unsigned long long sh_best;

    // ---- load 16 floats per thread, coalesced float4, nontemporal (read-once) ----
    const f4v* rowp = (const f4v*)(scores + (size_t)row * S_DIM);
    f4v v0 = __builtin_nontemporal_load(rowp + 0 * THREADS + t);
    f4v v1 = __builtin_nontemporal_load(rowp + 1 * THREADS + t);
    f4v v2 = __builtin_nontemporal_load(rowp + 2 * THREADS + t);
    f4v v3 = __builtin_nontemporal_load(rowp + 3 * THREADS + t);

    // ---- fused ones-fill: this block owns row `row`; write cols [64, 4096).
    // Disjoint from every scatter target (rank < 64), so no ordering hazard.
    {
        i4v* orow = (i4v*)(out + (size_t)row * S_DIM);
        const i4v ones = {1, 1, 1, 1};
        for (int j = 16 + t; j < S_DIM / 4; j += THREADS)
            __builtin_nontemporal_store(ones, orow + j);
    }

    // ---- monotonic u32 keys ----
    uint32_t key[EPT];
    {
        float f[EPT] = {v0[0], v0[1], v0[2], v0[3], v1[0], v1[1], v1[2], v1[3],
                        v2[0], v2[1], v2[2], v2[3], v3[0], v3[1], v3[2], v3[3]};
        #pragma unroll
        for (int i = 0; i < EPT; ++i) {
            uint32_t ub = __float_as_uint(f[i]);
            key[i] = (ub & 0x80000000u) ? ~ub : (ub | 0x80000000u);
        }
    }

    if (t == 0) sh_count = 0u;

    // ---- per-thread max of 16 keys ----
    uint32_t mx = key[0];
    #pragma unroll
    for (int i = 1; i < EPT; ++i) mx = max(mx, key[i]);

    // ---- wave-level bitonic sort (ascending by lane) of the 64 lane-maxes ----
    uint32_t x = mx;
    #pragma unroll
    for (int k = 2; k <= 64; k <<= 1) {
        #pragma unroll
        for (int j = k >> 1; j > 0; j >>= 1) {
            uint32_t v = __shfl_xor(x, j, 64);
            bool keepMin = (((lane & j) == 0) == ((lane & k) == 0));
            x = keepMin ? min(x, v) : max(x, v);
        }
    }
    // 16th largest lane-max sits at lane 48 (0-based rank 48 of ascending 64)
    uint32_t w16 = __shfl(x, 48, 64);
    if (lane == 0) sh_w16[wid] = w16;
    __syncthreads();                                    // barrier 1

    // Tc = min over waves; guaranteed >= 64 elements have key >= Tc, and Tc <= T64
    const uint32_t Tc = min(min(sh_w16[0], sh_w16[1]), min(sh_w16[2], sh_w16[3]));

    // ---- collect candidates: ballot compaction, 1 LDS atomic per wave ----
    uint32_t pred_bits = 0;
    #pragma unroll
    for (int i = 0; i < EPT; ++i)
        pred_bits |= (key[i] >= Tc) ? (1u << i) : 0u;
    uint32_t my_cnt = __popc(pred_bits);

    // inclusive wave prefix-sum of my_cnt over 64 lanes
    uint32_t pre = my_cnt;
    #pragma unroll
    for (int off = 1; off < 64; off <<= 1) {
        uint32_t n = __shfl_up(pre, off, 64);
        if (lane >= off) pre += n;
    }
    const uint32_t excl   = pre - my_cnt;
    const uint32_t wtotal = __shfl(pre, 63, 64);
    uint32_t wbase = 0;
    if (lane == 63) wbase = atomicAdd(&sh_count, wtotal);
    wbase = __shfl(wbase, 63, 64);

    uint32_t p = wbase + excl;
    #pragma unroll
    for (int i = 0; i < EPT; ++i) {
        if (pred_bits & (1u << i)) {
            uint32_t idx = (((uint32_t)(i >> 2) * THREADS + (uint32_t)t) << 2) | (uint32_t)(i & 3);
            if (p < CAND_CAP)
                cand[p] = ((unsigned long long)key[i] << 32) | (uint32_t)(~idx);
            ++p;
        }
    }
    __syncthreads();                                    // barrier 2
    const uint32_t m = sh_count;

    if (m <= CAND_CAP) {                                // block-uniform branch
        // ---- rank candidates (broadcast b128 LDS reads), scatter zeros ----
        if ((uint32_t)t < m) {
            unsigned long long me = cand[t];
            uint32_t rank = 0;
            const uint32_t mm = m & ~1u;
            for (uint32_t i = 0; i < mm; i += 2) {
                ulonglong2 c2 = *(const ulonglong2*)&cand[i];
                rank += (c2.x > me) ? 1u : 0u;
                rank += (c2.y > me) ? 1u : 0u;
            }
            if (m & 1u) rank += (cand[mm] > me) ? 1u : 0u;

            if (rank < K_TOP) {
                uint32_t idx = ~(uint32_t)me;
                // triangle (rows <= K, cols > row forced True) => skip iff idx < rank
                if (idx >= rank) {
                    __builtin_nontemporal_store(0,
                        &out[(size_t)b * ((size_t)S_DIM * S_DIM) + (size_t)idx * S_DIM + rank]);
                }
            }
        }
        return;
    }

    // ---- fallback (adversarial value-ties only): exact 64-round argmax extraction ----
    uint32_t used = 0u;
    for (int r = 0; r < K_TOP; ++r) {
        unsigned long long best = 0ull;
        #pragma unroll
        for (int i = 0; i < EPT; ++i) {
            if (!(used & (1u << i))) {
                uint32_t idx = (((uint32_t)(i >> 2) * THREADS + (uint32_t)t) << 2) | (uint32_t)(i & 3);
                unsigned long long ck = ((unsigned long long)key[i] << 32) | (uint32_t)(~idx);
                if (ck > best) best = ck;
            }
        }
        #pragma unroll
        for (int off = 32; off > 0; off >>= 1) {
            unsigned long long o = shfl_xor_u64(best, off);
            if (o > best) best = o;
        }
        if (lane == 0) sh_wbest[wid] = best;
        __syncthreads();
        if (t == 0) {
            unsigned long long bb = sh_wbest[0];
            for (int w = 1; w < 4; ++w) if (sh_wbest[w] > bb) bb = sh_wbest[w];
            sh_best = bb;
        }
        __syncthreads();
        const unsigned long long gb = sh_best;
        #pragma unroll
        for (int i = 0; i < EPT; ++i) {
            uint32_t idx = (((uint32_t)(i >> 2) * THREADS + (uint32_t)t) << 2) | (uint32_t)(i & 3);
            unsigned long long ck = ((unsigned long long)key[i] << 32) | (uint32_t)(~idx);
            if (ck == gb) {
                used |= (1u << i);
                uint32_t oidx = ~(uint32_t)gb;
                if (oidx >= (uint32_t)r) {
                    out[(size_t)b * ((size_t)S_DIM * S_DIM) + (size_t)oidx * S_DIM + r] = 0;
                }
            }
        }
        __syncthreads();
    }
}

extern "C" void kernel_launch(void* const* d_in, const int* in_sizes, int n_in,
                              void* d_out, int out_size, void* d_ws, size_t ws_size,
                              hipStream_t stream) {
    const float* scores = (const float*)d_in[0];
    int* out = (int*)d_out;

    const int B = in_sizes[0] / (S_DIM * S_DIM);   // 4 (in_sizes is element count)
    const int nrows = B * S_DIM;                   // 16384

    // Phase 1: ones into the scatter-target strip (cols [0,64)) — 4 MiB.
    const int prefill_threads = nrows * 16;        // one int4 per thread
    hipLaunchKernelGGL(prefill_edge_kernel, dim3((prefill_threads + THREADS - 1) / THREADS),
                       dim3(THREADS), 0, stream, (i4v*)out, nrows);

    // Phase 2: fused {row ones-fill (cols >= 64) + topk + scatter}.
    hipLaunchKernelGGL(topk_scatter_kernel, dim3(nrows), dim3(THREADS), 0, stream,
                       scores, out);
}

// Round 5
// 434.137 us; speedup vs baseline: 1.0925x; 1.0925x over previous
//
#include <hip/hip_runtime.h>
#include <stdint.h>

#define S_DIM 4096
#define K_TOP 64
#define THREADS 256
#define EPT 16           // elements per thread = 4096/256
#define CAND_CAP 256

// Pre-fill ones into the scatter-target strip only: cols [0,64) of every row.
// B*S rows * 64 ints = 4 MiB. Must complete before any scatter (same stream
// => serialized). One int4 (16 B) per thread. Plain stores: lines stay in L2,
// so the later scattered 4B zero-writes merge cheaply (nt here cost +39us in R4).
__global__ __launch_bounds__(256) void prefill_edge_kernel(int4* __restrict__ out, int nrows) {
    int L = blockIdx.x * blockDim.x + threadIdx.x;   // 0 .. nrows*16-1
    if (L >= nrows * 16) return;
    int row = L >> 4;          // global row (b*S + s)
    int q   = L & 15;          // which int4 within the first 64 ints
    out[(size_t)row * (S_DIM / 4) + q] = make_int4(1, 1, 1, 1);
}

__device__ __forceinline__ unsigned long long shfl_xor_u64(unsigned long long v, int m) {
    uint32_t lo = (uint32_t)v, hi = (uint32_t)(v >> 32);
    lo = __shfl_xor(lo, m, 64);
    hi = __shfl_xor(hi, m, 64);
    return ((unsigned long long)hi << 32) | lo;
}

__global__ __launch_bounds__(256) void topk_scatter_kernel(const float* __restrict__ scores,
                                                           int* __restrict__ out) {
    const int row  = blockIdx.x;          // b*S + s
    const int b    = row >> 12;           // row / 4096
    const int t    = threadIdx.x;
    const int lane = t & 63;
    const int wid  = t >> 6;

    __shared__ uint32_t sh_w16[4];
    __shared__ __align__(16) unsigned long long cand[CAND_CAP];
    __shared__ uint32_t sh_count;
    __shared__ unsigned long long sh_wbest[4];
    __shared__ unsigned long long sh_best;

    // ---- load 16 floats per thread, coalesced float4 (plain loads) ----
    const float4* rowp = (const float4*)(scores + (size_t)row * S_DIM);
    float4 v0 = rowp[0 * THREADS + t];
    float4 v1 = rowp[1 * THREADS + t];
    float4 v2 = rowp[2 * THREADS + t];
    float4 v3 = rowp[3 * THREADS + t];

    // ---- fused ones-fill: this block owns row `row`; write cols [64, 4096).
    // Disjoint from every scatter target (rank < 64), so no ordering hazard.
    {
        int4* orow = (int4*)(out + (size_t)row * S_DIM);
        const int4 ones = make_int4(1, 1, 1, 1);
        for (int j = 16 + t; j < S_DIM / 4; j += THREADS) orow[j] = ones;
    }

    // ---- monotonic u32 keys ----
    uint32_t key[EPT];
    {
        float f[EPT] = {v0.x, v0.y, v0.z, v0.w, v1.x, v1.y, v1.z, v1.w,
                        v2.x, v2.y, v2.z, v2.w, v3.x, v3.y, v3.z, v3.w};
        #pragma unroll
        for (int i = 0; i < EPT; ++i) {
            uint32_t ub = __float_as_uint(f[i]);
            key[i] = (ub & 0x80000000u) ? ~ub : (ub | 0x80000000u);
        }
    }

    if (t == 0) sh_count = 0u;

    // ---- per-thread max of 16 keys ----
    uint32_t mx = key[0];
    #pragma unroll
    for (int i = 1; i < EPT; ++i) mx = max(mx, key[i]);

    // ---- wave-level bitonic sort (ascending by lane) of the 64 lane-maxes ----
    uint32_t x = mx;
    #pragma unroll
    for (int k = 2; k <= 64; k <<= 1) {
        #pragma unroll
        for (int j = k >> 1; j > 0; j >>= 1) {
            uint32_t v = __shfl_xor(x, j, 64);
            bool keepMin = (((lane & j) == 0) == ((lane & k) == 0));
            x = keepMin ? min(x, v) : max(x, v);
        }
    }
    // 16th largest lane-max sits at lane 48 (0-based rank 48 of ascending 64)
    uint32_t w16 = __shfl(x, 48, 64);
    if (lane == 0) sh_w16[wid] = w16;
    __syncthreads();                                    // barrier 1

    // Tc = min over waves; guaranteed >= 64 elements have key >= Tc, and Tc <= T64
    const uint32_t Tc = min(min(sh_w16[0], sh_w16[1]), min(sh_w16[2], sh_w16[3]));

    // ---- collect candidates: ballot compaction, 1 LDS atomic per wave ----
    uint32_t pred_bits = 0;
    #pragma unroll
    for (int i = 0; i < EPT; ++i)
        pred_bits |= (key[i] >= Tc) ? (1u << i) : 0u;
    uint32_t my_cnt = __popc(pred_bits);

    // inclusive wave prefix-sum of my_cnt over 64 lanes
    uint32_t pre = my_cnt;
    #pragma unroll
    for (int off = 1; off < 64; off <<= 1) {
        uint32_t n = __shfl_up(pre, off, 64);
        if (lane >= off) pre += n;
    }
    const uint32_t excl   = pre - my_cnt;
    const uint32_t wtotal = __shfl(pre, 63, 64);
    uint32_t wbase = 0;
    if (lane == 63) wbase = atomicAdd(&sh_count, wtotal);
    wbase = __shfl(wbase, 63, 64);

    uint32_t p = wbase + excl;
    #pragma unroll
    for (int i = 0; i < EPT; ++i) {
        if (pred_bits & (1u << i)) {
            uint32_t idx = (((uint32_t)(i >> 2) * THREADS + (uint32_t)t) << 2) | (uint32_t)(i & 3);
            if (p < CAND_CAP)
                cand[p] = ((unsigned long long)key[i] << 32) | (uint32_t)(~idx);
            ++p;
        }
    }
    __syncthreads();                                    // barrier 2
    const uint32_t m = sh_count;

    if (m <= CAND_CAP) {                                // block-uniform branch
        // ---- rank candidates (broadcast b128 LDS reads), scatter zeros ----
        if ((uint32_t)t < m) {
            unsigned long long me = cand[t];
            uint32_t rank = 0;
            const uint32_t mm = m & ~1u;
            for (uint32_t i = 0; i < mm; i += 2) {
                ulonglong2 c2 = *(const ulonglong2*)&cand[i];
                rank += (c2.x > me) ? 1u : 0u;
                rank += (c2.y > me) ? 1u : 0u;
            }
            if (m & 1u) rank += (cand[mm] > me) ? 1u : 0u;

            if (rank < K_TOP) {
                uint32_t idx = ~(uint32_t)me;
                // triangle (rows <= K, cols > row forced True) => skip iff idx < rank
                if (idx >= rank) {
                    out[(size_t)b * ((size_t)S_DIM * S_DIM) + (size_t)idx * S_DIM + rank] = 0;
                }
            }
        }
        return;
    }

    // ---- fallback (adversarial value-ties only): exact 64-round argmax extraction ----
    uint32_t used = 0u;
    for (int r = 0; r < K_TOP; ++r) {
        unsigned long long best = 0ull;
        #pragma unroll
        for (int i = 0; i < EPT; ++i) {
            if (!(used & (1u << i))) {
                uint32_t idx = (((uint32_t)(i >> 2) * THREADS + (uint32_t)t) << 2) | (uint32_t)(i & 3);
                unsigned long long ck = ((unsigned long long)key[i] << 32) | (uint32_t)(~idx);
                if (ck > best) best = ck;
            }
        }
        #pragma unroll
        for (int off = 32; off > 0; off >>= 1) {
            unsigned long long o = shfl_xor_u64(best, off);
            if (o > best) best = o;
        }
        if (lane == 0) sh_wbest[wid] = best;
        __syncthreads();
        if (t == 0) {
            unsigned long long bb = sh_wbest[0];
            for (int w = 1; w < 4; ++w) if (sh_wbest[w] > bb) bb = sh_wbest[w];
            sh_best = bb;
        }
        __syncthreads();
        const unsigned long long gb = sh_best;
        #pragma unroll
        for (int i = 0; i < EPT; ++i) {
            uint32_t idx = (((uint32_t)(i >> 2) * THREADS + (uint32_t)t) << 2) | (uint32_t)(i & 3);
            unsigned long long ck = ((unsigned long long)key[i] << 32) | (uint32_t)(~idx);
            if (ck == gb) {
                used |= (1u << i);
                uint32_t oidx = ~(uint32_t)gb;
                if (oidx >= (uint32_t)r) {
                    out[(size_t)b * ((size_t)S_DIM * S_DIM) + (size_t)oidx * S_DIM + r] = 0;
                }
            }
        }
        __syncthreads();
    }
}

extern "C" void kernel_launch(void* const* d_in, const int* in_sizes, int n_in,
                              void* d_out, int out_size, void* d_ws, size_t ws_size,
                              hipStream_t stream) {
    const float* scores = (const float*)d_in[0];
    int* out = (int*)d_out;

    const int B = in_sizes[0] / (S_DIM * S_DIM);   // 4 (in_sizes is element count)
    const int nrows = B * S_DIM;                   // 16384

    // Phase 1: ones into the scatter-target strip (cols [0,64)) — 4 MiB.
    const int prefill_threads = nrows * 16;        // one int4 per thread
    hipLaunchKernelGGL(prefill_edge_kernel, dim3((prefill_threads + THREADS - 1) / THREADS),
                       dim3(THREADS), 0, stream, (int4*)out, nrows);

    // Phase 2: fused {row ones-fill (cols >= 64) + topk + scatter}.
    hipLaunchKernelGGL(topk_scatter_kernel, dim3(nrows), dim3(THREADS), 0, stream,
                       scores, out);
}